// Round 12
// baseline (133.643 us; speedup 1.0000x reference)
//
#include <hip/hip_runtime.h>
#include <hip/hip_bf16.h>

// EdgeNetwork fused, round 8: two-phase, NO f32 atomics.
//   Evidence (R3=55us, R6=60us, R7=64us with wildly different compute): wall is
//   the 6.4M device-scope f32 atomicAdds (memory-side RMW, ~107 G/s). Replace:
//   k1 build:    linked list per atom: nxt[e]=atomicExch(&head[src[e]],e)  (100K int atomics)
//   k2 transform: R6 compute (W reg-cached, 4-way K-split), epilogue = plain
//                 coalesced stores of per-edge rows into ws (25.6MB streaming)
//   k3 gather:   one wave per atom walks its chain (avg deg 2), lane=col,
//                 scratch is L3-resident; writes out directly (deg-0 -> 0).
// Fallback to the proven R6 atomic kernel if ws_size is too small.

#define N_ATOMS   50000
#define N_EDGES   100000
#define DIM       64
#define BDIM      16
#define TILE      32
#define NTILES    (N_EDGES / TILE)      // 3125
#define BLOCK     512
#define GRID      256
#define NKS       20                    // 5 channels x 4 ksteps per wave

// ---- LDS map: NB f32[32][64] swizzled, BOND f32[32][20], SRC int[32], COMB f32[16][64] ----
#define NB_OFF(p)        ((p) * 8192)                                  // [0, 16384)
#define BOND_OFF(p)      (16384 + (p) * 2560)                          // [16384, 21504)
#define SRC_OFF(p)       (21504 + (p) * 128)                           // [21504, 21760)
#define COMB_OFF(p,h,qq) (21760 + ((((p)*2+(h))*3)+(qq)) * 4096)       // [21760, 70912)
#define LDS_TOTAL        70912

typedef __bf16 bf16x8 __attribute__((ext_vector_type(8)));
typedef float  f32x16 __attribute__((ext_vector_type(16)));

// ===================== shared compute body (templated on epilogue) =====================
// EPI = 0: store rows to tr (two-phase).  EPI = 1: atomicAdd to out via srcs (fallback).
template <int EPI>
__device__ __forceinline__
void edge_body(const float* __restrict__ atom, const float* __restrict__ bondf,
               const int* __restrict__ pair, const float* __restrict__ kmat,
               const float* __restrict__ bias, float* __restrict__ dstbuf)
{
    extern __shared__ char smem[];
    const int tid = threadIdx.x;
    const int l   = tid & 63;
    const int wid = tid >> 6;
    const int q   = wid >> 1;          // K quarter 0..3 (channels q*5 .. q*5+4)
    const int h   = wid & 1;           // N-half
    const int ma  = l & 31;
    const int hi  = l >> 5;
    const int n   = h * 32 + (l & 31);

    // W fragments -> registers (one-time, L2-resident)
    bf16x8 wfr[NKS];
    #pragma unroll
    for (int ci = 0; ci < 5; ++ci) {
        const int c = q * 5 + ci;
        #pragma unroll
        for (int ss = 0; ss < 4; ++ss) {
            bf16x8 w;
            if (c < 17) {
                const float* src = (c < BDIM) ? (kmat + c * (DIM * DIM) + n * DIM + ss * 16 + hi * 8)
                                              : (bias + n * DIM + ss * 16 + hi * 8);
                float4 v0 = *(const float4*)(src);
                float4 v1 = *(const float4*)(src + 4);
                w[0] = (__bf16)v0.x; w[1] = (__bf16)v0.y; w[2] = (__bf16)v0.z; w[3] = (__bf16)v0.w;
                w[4] = (__bf16)v1.x; w[5] = (__bf16)v1.y; w[6] = (__bf16)v1.z; w[7] = (__bf16)v1.w;
            } else {
                #pragma unroll
                for (int j = 0; j < 8; ++j) w[j] = (__bf16)0.0f;
            }
            wfr[ci * 4 + ss] = w;
        }
    }

    auto stage = [&](int stile, int pbuf) {
        const int sm = tid >> 4, sp = tid & 15;
        const int e  = stile * TILE + sm;
        const int dst = pair[2 * e + 1];
        float4 v = *(const float4*)(atom + dst * DIM + sp * 4);
        float* nbb = (float*)(smem + NB_OFF(pbuf));
        *(float4*)(nbb + sm * 64 + ((sp ^ (sm & 7)) << 2)) = v;
        float* bb = (float*)(smem + BOND_OFF(pbuf));
        bb[sm * 20 + sp] = bondf[e * BDIM + sp];
        if (sp == 0) {
            bb[sm * 20 + 16] = 1.0f;
            if (EPI == 1) ((int*)(smem + SRC_OFF(pbuf)))[sm] = pair[2 * e];
        } else if (sp < 4) {
            bb[sm * 20 + 16 + sp] = 0.0f;
        }
    };

    int tile = blockIdx.x;
    stage(tile, 0);
    __syncthreads();
    int p = 0;

    while (true) {
        const int  ntile = tile + GRID;
        const bool more  = (ntile < NTILES);
        if (more) stage(ntile, p ^ 1);

        const float* nbb = (const float*)(smem + NB_OFF(p));
        const float* bb  = (const float*)(smem + BOND_OFF(p));

        float nbf[32];
        #pragma unroll
        for (int ss = 0; ss < 4; ++ss) {
            const int cb = ss * 4 + hi * 2;
            float4 u0 = *(const float4*)(nbb + ma * 64 + (((cb    ) ^ (ma & 7)) << 2));
            float4 u1 = *(const float4*)(nbb + ma * 64 + (((cb + 1) ^ (ma & 7)) << 2));
            nbf[ss*8+0] = u0.x; nbf[ss*8+1] = u0.y; nbf[ss*8+2] = u0.z; nbf[ss*8+3] = u0.w;
            nbf[ss*8+4] = u1.x; nbf[ss*8+5] = u1.y; nbf[ss*8+6] = u1.z; nbf[ss*8+7] = u1.w;
        }
        float bnd[5];
        #pragma unroll
        for (int ci = 0; ci < 5; ++ci) bnd[ci] = bb[ma * 20 + q * 5 + ci];

        f32x16 ac0, ac1;
        #pragma unroll
        for (int i = 0; i < 16; ++i) { ac0[i] = 0.0f; ac1[i] = 0.0f; }

        #pragma unroll
        for (int ks = 0; ks < NKS; ++ks) {
            const int ci = ks >> 2, ss = ks & 3;
            const float bv = bnd[ci];
            bf16x8 a;
            a[0] = (__bf16)(bv * nbf[ss*8+0]); a[1] = (__bf16)(bv * nbf[ss*8+1]);
            a[2] = (__bf16)(bv * nbf[ss*8+2]); a[3] = (__bf16)(bv * nbf[ss*8+3]);
            a[4] = (__bf16)(bv * nbf[ss*8+4]); a[5] = (__bf16)(bv * nbf[ss*8+5]);
            a[6] = (__bf16)(bv * nbf[ss*8+6]); a[7] = (__bf16)(bv * nbf[ss*8+7]);
            if (ks & 1) ac1 = __builtin_amdgcn_mfma_f32_32x32x16_bf16(a, wfr[ks], ac1, 0, 0, 0);
            else        ac0 = __builtin_amdgcn_mfma_f32_32x32x16_bf16(a, wfr[ks], ac0, 0, 0, 0);
        }
        #pragma unroll
        for (int r = 0; r < 16; ++r) ac0[r] += ac1[r];

        int oaddr[16];
        if (q == 0) {
            if (EPI == 1) {
                const int* sr = (const int*)(smem + SRC_OFF(p));
                #pragma unroll
                for (int r = 0; r < 16; ++r) {
                    const int m = (r & 3) + 8 * (r >> 2) + 4 * hi;
                    oaddr[r] = sr[m] * DIM + n;
                }
            }
        } else {
            float* cbw = (float*)(smem + COMB_OFF(p, h, q - 1));
            #pragma unroll
            for (int r = 0; r < 16; ++r) cbw[r * 64 + l] = ac0[r];
        }

        __syncthreads();

        if (q == 0) {
            const float* c0 = (const float*)(smem + COMB_OFF(p, h, 0));
            const float* c1 = (const float*)(smem + COMB_OFF(p, h, 1));
            const float* c2 = (const float*)(smem + COMB_OFF(p, h, 2));
            #pragma unroll
            for (int r = 0; r < 16; ++r) {
                const float val = ac0[r] + c0[r*64+l] + c1[r*64+l] + c2[r*64+l];
                if (EPI == 0) {
                    const int m = (r & 3) + 8 * (r >> 2) + 4 * hi;
                    dstbuf[(size_t)(tile * TILE + m) * DIM + n] = val;   // plain coalesced store
                } else {
                    atomicAdd(dstbuf + oaddr[r], val);
                }
            }
        }
        if (!more) break;
        tile = ntile; p ^= 1;
    }
}

__global__ __launch_bounds__(BLOCK, 2)
void edge_transform_kernel(const float* __restrict__ atom, const float* __restrict__ bondf,
                           const int* __restrict__ pair, const float* __restrict__ kmat,
                           const float* __restrict__ bias, float* __restrict__ tr)
{ edge_body<0>(atom, bondf, pair, kmat, bias, tr); }

__global__ __launch_bounds__(BLOCK, 2)
void edge_atomic_kernel(const float* __restrict__ atom, const float* __restrict__ bondf,
                        const int* __restrict__ pair, const float* __restrict__ kmat,
                        const float* __restrict__ bias, float* __restrict__ out)
{ edge_body<1>(atom, bondf, pair, kmat, bias, out); }

// ===================== linked-list build + gather =====================
__global__ __launch_bounds__(256)
void build_kernel(const int* __restrict__ pair, int* __restrict__ head, int* __restrict__ nxt)
{
    const int e = blockIdx.x * 256 + threadIdx.x;
    if (e < N_EDGES)
        nxt[e] = atomicExch(&head[pair[2 * e]], e);
}

__global__ __launch_bounds__(256)
void gather_kernel(const int* __restrict__ head, const int* __restrict__ nxt,
                   const float* __restrict__ tr, float* __restrict__ out)
{
    const int a = blockIdx.x * 4 + (threadIdx.x >> 6);   // one wave per atom
    const int l = threadIdx.x & 63;                      // lane = column
    float acc = 0.0f;
    int e = head[a];                                     // wave-uniform broadcast
    while (e >= 0) {
        acc += tr[(size_t)e * DIM + l];                  // coalesced 256B row
        e = nxt[e];
    }
    out[(size_t)a * DIM + l] = acc;
}

extern "C" void kernel_launch(void* const* d_in, const int* in_sizes, int n_in,
                              void* d_out, int out_size, void* d_ws, size_t ws_size,
                              hipStream_t stream)
{
    const float* atom  = (const float*)d_in[0];
    const float* bondf = (const float*)d_in[1];
    const int*   pair  = (const int*)  d_in[2];
    const float* kmat  = (const float*)d_in[3];
    const float* bias  = (const float*)d_in[4];
    float* out = (float*)d_out;

    const size_t tr_bytes   = (size_t)N_EDGES * DIM * sizeof(float);   // 25.6 MB
    const size_t head_bytes = (size_t)N_ATOMS * sizeof(int);           // 200 KB
    const size_t nxt_bytes  = (size_t)N_EDGES * sizeof(int);           // 400 KB
    const size_t need = tr_bytes + head_bytes + nxt_bytes;

    if (ws_size >= need) {
        float* tr  = (float*)d_ws;
        int* head  = (int*)((char*)d_ws + tr_bytes);
        int* nxt   = head + N_ATOMS;

        hipFuncSetAttribute((const void*)edge_transform_kernel,
                            hipFuncAttributeMaxDynamicSharedMemorySize, LDS_TOTAL);
        hipMemsetAsync(head, 0xFF, head_bytes, stream);                // head = -1
        build_kernel<<<(N_EDGES + 255) / 256, 256, 0, stream>>>(pair, head, nxt);
        edge_transform_kernel<<<GRID, BLOCK, LDS_TOTAL, stream>>>(atom, bondf, pair, kmat, bias, tr);
        gather_kernel<<<N_ATOMS / 4, 256, 0, stream>>>(head, nxt, tr, out);
    } else {
        // fallback: proven round-6 atomic path
        hipFuncSetAttribute((const void*)edge_atomic_kernel,
                            hipFuncAttributeMaxDynamicSharedMemorySize, LDS_TOTAL);
        hipMemsetAsync(out, 0, (size_t)out_size * sizeof(float), stream);
        edge_atomic_kernel<<<GRID, BLOCK, LDS_TOTAL, stream>>>(atom, bondf, pair, kmat, bias, out);
    }
}